// Round 9
// baseline (957.253 us; speedup 1.0000x reference)
//
#include <hip/hip_runtime.h>
#include <cstdint>

#define TT 300   // timesteps
#define TC 75    // TT/4
#define NBATCH 4

// PSP + refractory IIR step, exact op order of the reference scan.
__device__ __forceinline__ void psp_step(float z, float& gp, float& hp, float& gr, float& hr, float& s_out) {
    hp = 0.90483741803595957f * (hp + gp);      // a_sr = exp(-1/10)
    gp = 0.90483741803595957f * gp + z;
    hr = 0.36787944117144233f * (hr + gr);      // a_rf = exp(-1)
    gr = 0.36787944117144233f * gr;
    float u = 0.27182818284590452f * hp + (-54.365636569180904f) * hr; // c_sr*hp + c_rf*hr
    float s = (u >= 10.0f) ? 1.0f : 0.0f;
    gr += s;
    s_out = s;
}

// Coalesced R-way partial reduce: zr[p][t] = sum_r z[r*pstride + p*TT + t].
template <int R>
__global__ void k_reduce(const float* __restrict__ z, float* __restrict__ zr,
                         int total4, int pstride) {
    int i = blockIdx.x * 256 + threadIdx.x;
    if (i >= total4) return;
    size_t pos = (size_t)i * 4;
    float4 a = *(const float4*)(z + pos);
#pragma unroll
    for (int r = 1; r < R; ++r) {
        float4 b = *(const float4*)(z + (size_t)r * pstride + pos);
        a.x += b.x; a.y += b.y; a.z += b.z; a.w += b.w;
    }
    *(float4*)(zr + pos) = a;
}

// Per-neuron scan over T with fused R-way partial reduce, 12-step chunks.
template <int R>
__global__ void k_scan_redp(const float* __restrict__ z, float* __restrict__ s,
                            int n_neur, int pstride) {
    int i = blockIdx.x * 64 + threadIdx.x;
    if (i >= n_neur) return;
    const float* zp = z + (size_t)i * TT;
    float* sp = s + (size_t)i * TT;
    float gp = 0.f, hp = 0.f, gr = 0.f, hr = 0.f;
#pragma unroll 1
    for (int c = 0; c < 25; ++c) {
        const float* p = zp + c * 12;
        float4 a0 = *(const float4*)(p);
        float4 a1 = *(const float4*)(p + 4);
        float4 a2 = *(const float4*)(p + 8);
#pragma unroll
        for (int r = 1; r < R; ++r) {
            const float* pr = p + (size_t)r * pstride;
            float4 b0 = *(const float4*)(pr);
            float4 b1 = *(const float4*)(pr + 4);
            float4 b2 = *(const float4*)(pr + 8);
            a0.x += b0.x; a0.y += b0.y; a0.z += b0.z; a0.w += b0.w;
            a1.x += b1.x; a1.y += b1.y; a1.z += b1.z; a1.w += b1.w;
            a2.x += b2.x; a2.y += b2.y; a2.z += b2.z; a2.w += b2.w;
        }
        float4 o0, o1, o2;
        psp_step(a0.x, gp, hp, gr, hr, o0.x);
        psp_step(a0.y, gp, hp, gr, hr, o0.y);
        psp_step(a0.z, gp, hp, gr, hr, o0.z);
        psp_step(a0.w, gp, hp, gr, hr, o0.w);
        psp_step(a1.x, gp, hp, gr, hr, o1.x);
        psp_step(a1.y, gp, hp, gr, hr, o1.y);
        psp_step(a1.z, gp, hp, gr, hr, o1.z);
        psp_step(a1.w, gp, hp, gr, hr, o1.w);
        psp_step(a2.x, gp, hp, gr, hr, o2.x);
        psp_step(a2.y, gp, hp, gr, hr, o2.y);
        psp_step(a2.z, gp, hp, gr, hr, o2.z);
        psp_step(a2.w, gp, hp, gr, hr, o2.w);
        float* q = sp + c * 12;
        *(float4*)(q) = o0;
        *(float4*)(q + 4) = o1;
        *(float4*)(q + 8) = o2;
    }
}

// Fused scan-pool-scan, thread per CONV neuron; quad pool via shfl_xor (exact on 0/1 spikes).
template <int R, int C, int H2, int W2>
__global__ void __launch_bounds__(256) k_spsq(const float* __restrict__ z,
                                              float* __restrict__ s, int pstride) {
    constexpr int H = 2 * H2, W = 2 * W2;
    int i = blockIdx.x * 256 + threadIdx.x;   // grid exact: NBATCH*C*H*W threads
    int q  = i & 3;
    int p  = i >> 2;
    int x2 = p % W2;
    int y2 = (p / W2) % H2;
    int c  = (p / (W2 * H2)) % C;
    int n  = p / (W2 * H2 * C);
    int dy = q >> 1, dx = q & 1;
    const float* zp = z + (((size_t)(n * C + c) * H + 2 * y2 + dy) * W + 2 * x2 + dx) * TT;
    float* so = s + (size_t)p * TT;
    float gp = 0.f, hp = 0.f, gr = 0.f, hr = 0.f;   // conv neuron IIR
    float Gp = 0.f, Hp = 0.f, Gr = 0.f, Hr = 0.f;   // pooled neuron IIR
#pragma unroll 1
    for (int cc = 0; cc < 25; ++cc) {
        const float* pp = zp + cc * 12;
        float4 a0 = *(const float4*)(pp);
        float4 a1 = *(const float4*)(pp + 4);
        float4 a2 = *(const float4*)(pp + 8);
#pragma unroll
        for (int r = 1; r < R; ++r) {
            const float* pr = pp + (size_t)r * pstride;
            float4 b0 = *(const float4*)(pr);
            float4 b1 = *(const float4*)(pr + 4);
            float4 b2 = *(const float4*)(pr + 8);
            a0.x += b0.x; a0.y += b0.y; a0.z += b0.z; a0.w += b0.w;
            a1.x += b1.x; a1.y += b1.y; a1.z += b1.z; a1.w += b1.w;
            a2.x += b2.x; a2.y += b2.y; a2.z += b2.z; a2.w += b2.w;
        }
        float zv[12] = {a0.x, a0.y, a0.z, a0.w, a1.x, a1.y, a1.z, a1.w, a2.x, a2.y, a2.z, a2.w};
        float ov[12];
#pragma unroll
        for (int tt = 0; tt < 12; ++tt) {
            float sq;
            psp_step(zv[tt], gp, hp, gr, hr, sq);
            float t1 = sq + __shfl_xor(sq, 1, 64);
            float pool = t1 + __shfl_xor(t1, 2, 64);
            psp_step(11.0f * pool, Gp, Hp, Gr, Hr, ov[tt]);
        }
        if (q == 0) {
            float* qo = so + cc * 12;
            *(float4*)(qo)     = make_float4(ov[0], ov[1], ov[2],  ov[3]);
            *(float4*)(qo + 4) = make_float4(ov[4], ov[5], ov[6],  ov[7]);
            *(float4*)(qo + 8) = make_float4(ov[8], ov[9], ov[10], ov[11]);
        }
    }
}

// Fully fused L1: conv 5x5 (2->32, 32x32, pad 2) + psp + 2x2 pool + psp -> s2 directly.
// Eliminates z1 (157 MB write + 157 MB read) and one dispatch.
// Block: 256 thr, i = g(1b)<<7 | co(5b)<<2 | q(2b). Covers 2 horizontally-adjacent pool
// quads (x2 = 2*xp+g) for all 32 co. Grid: 4n x 16y2 x 8xp = 512 blocks.
// Per 12-step chunk: stage 2ci x 6y x 8x halo tile x 12t (4.6 KB) to LDS, then each
// thread does 50 taps (weights in regs) x 12t FMA + 12 IIR steps + quad-pool shfl.
__global__ void __launch_bounds__(256) k_conv1_fused(const float* __restrict__ s0,
                                                     const float* __restrict__ w1,
                                                     float* __restrict__ s2) {
    __shared__ float tile[2 * 6 * 8 * 12];   // slot s = ((ci*6+yy)*8+xx)*3+third, float4 each
    int b  = blockIdx.x;
    int n  = b >> 7;
    int y2 = (b >> 3) & 15;
    int xp = b & 7;
    int i  = threadIdx.x;
    int q  = i & 3;
    int co = (i >> 2) & 31;
    int g  = i >> 7;
    int dy = q >> 1, dx = q & 1;
    int x2 = 2 * xp + g;
    float wr[50];
#pragma unroll
    for (int t = 0; t < 50; ++t) wr[t] = w1[co * 50 + t];
    float* so = s2 + (((size_t)(n * 32 + co) * 16 + y2) * 16 + x2) * TT;
    float gp = 0.f, hp = 0.f, gr = 0.f, hr = 0.f;   // conv neuron IIR
    float Gp = 0.f, Hp = 0.f, Gr = 0.f, Hr = 0.f;   // pooled neuron IIR
#pragma unroll 1
    for (int cc = 0; cc < 25; ++cc) {
        __syncthreads();
        // stage: 288 float4 slots; thread i stages slot i (+ slot i+256 if i<32)
#pragma unroll
        for (int rep = 0; rep < 2; ++rep) {
            int s = i + rep * 256;
            if (s < 288) {
                int ci = s / 144;
                int r  = s - ci * 144;
                int yy = r / 24;
                int r2 = r - yy * 24;
                int xx = r2 / 3;
                int th = r2 - xx * 3;
                int gy = 2 * y2 - 2 + yy;
                int gx = 4 * xp - 2 + xx;
                float4 v = make_float4(0.f, 0.f, 0.f, 0.f);
                if (gy >= 0 && gy < 32 && gx >= 0 && gx < 32)
                    v = *(const float4*)(s0 + (((size_t)(n * 2 + ci) * 32 + gy) * 32 + gx) * TT + cc * 12 + th * 4);
                ((float4*)tile)[s] = v;
            }
        }
        __syncthreads();
        float za[12];
#pragma unroll
        for (int t = 0; t < 12; ++t) za[t] = 0.f;
#pragma unroll
        for (int ci = 0; ci < 2; ++ci)
#pragma unroll
            for (int ky = 0; ky < 5; ++ky)
#pragma unroll
                for (int kx = 0; kx < 5; ++kx) {
                    int base = ((ci * 6 + (dy + ky)) * 8 + (2 * g + dx + kx)) * 3;
                    float w = wr[ci * 25 + ky * 5 + kx];
                    float4 v0 = ((float4*)tile)[base];
                    float4 v1 = ((float4*)tile)[base + 1];
                    float4 v2 = ((float4*)tile)[base + 2];
                    za[0] += w * v0.x; za[1]  += w * v0.y; za[2]  += w * v0.z; za[3]  += w * v0.w;
                    za[4] += w * v1.x; za[5]  += w * v1.y; za[6]  += w * v1.z; za[7]  += w * v1.w;
                    za[8] += w * v2.x; za[9]  += w * v2.y; za[10] += w * v2.z; za[11] += w * v2.w;
                }
        float ov[12];
#pragma unroll
        for (int tt = 0; tt < 12; ++tt) {
            float sq;
            psp_step(za[tt], gp, hp, gr, hr, sq);
            float t1 = sq + __shfl_xor(sq, 1, 64);
            float pool = t1 + __shfl_xor(t1, 2, 64);
            psp_step(11.0f * pool, Gp, Hp, Gr, Hr, ov[tt]);
        }
        if (q == 0) {
            float* qo = so + cc * 12;
            *(float4*)(qo)     = make_float4(ov[0], ov[1], ov[2],  ov[3]);
            *(float4*)(qo + 4) = make_float4(ov[4], ov[5], ov[6],  ov[7]);
            *(float4*)(qo + 8) = make_float4(ov[8], ov[9], ov[10], ov[11]);
        }
    }
}

// Transpose-pack OIHW weights (COUT, S) -> [s][COUT] so one tap's weights are contiguous.
__global__ void k_pack_w(const float* __restrict__ w, float* __restrict__ wp, int S, int CO, int total) {
    int i = blockIdx.x * 256 + threadIdx.x;
    if (i >= total) return;
    int co = i % CO, s = i / CO;
    wp[i] = w[co * S + s];
}

// 4x4 sum-pool * 11.0 over (N,2,128,128,T) -> z (N,2,32,32,T). Thread = (p, tc), tc fastest.
__global__ void k_pool4(const float* __restrict__ x, float* __restrict__ z) {
    int idx = blockIdx.x * 256 + threadIdx.x;
    if (idx >= NBATCH * 2 * 32 * 32 * TC) return;
    int tc = idx % TC;
    int p  = idx / TC;
    int w  = p % 32;
    int h  = (p / 32) % 32;
    int nc = p / (32 * 32);
    const float* base = x + (((size_t)nc * 128 + h * 4) * 128 + w * 4) * TT + tc * 4;
    float ax = 0.f, ay = 0.f, az = 0.f, aw = 0.f;
#pragma unroll
    for (int i = 0; i < 4; ++i)
#pragma unroll
        for (int j = 0; j < 4; ++j) {
            float4 v = *(const float4*)(base + ((size_t)i * 128 + j) * TT);
            ax += v.x; ay += v.y; az += v.z; aw += v.w;
        }
    float4 o; o.x = 11.0f * ax; o.y = 11.0f * ay; o.z = 11.0f * az; o.w = 11.0f * aw;
    *(float4*)(z + (size_t)p * TT + tc * 4) = o;
}

// LDS-weight conv. Thread = (sp, n, y, x, cb, tc); cb adjacent to tc for input reuse.
template <int SPLIT, int CIN, int COUT, int H, int W, int K, int PAD>
__global__ void __launch_bounds__(256) k_conv_lds(const float* __restrict__ s_in,
                                                  const float* __restrict__ wp,
                                                  float* __restrict__ z) {
    constexpr int CBN = COUT / 16;
    constexpr int CIN_SP = CIN / SPLIT;
    constexpr int S_SP = CIN_SP * K * K;
    __shared__ float wlds[S_SP * COUT];
    int sp = (int)(((size_t)blockIdx.x * 256) / (CBN * NBATCH * H * W * TC));
    {
        const float4* src = (const float4*)(wp + (size_t)sp * S_SP * COUT);
        float4* dst = (float4*)wlds;
        for (int i = threadIdx.x; i < S_SP * COUT / 4; i += 256) dst[i] = src[i];
    }
    __syncthreads();
    int t = blockIdx.x * 256 + threadIdx.x;
    int tc = t % TC;     t /= TC;
    int cb = t % CBN;    t /= CBN;
    int x  = t % W;      t /= W;
    int y  = t % H;      t /= H;
    int n  = t % NBATCH;
    const float* sb = s_in + ((size_t)n * CIN + sp * CIN_SP) * H * W * TT + tc * 4;
    float acc[4][4][4]; // [cg][c][t]
#pragma unroll
    for (int a = 0; a < 4; ++a)
#pragma unroll
        for (int b = 0; b < 4; ++b)
#pragma unroll
            for (int d = 0; d < 4; ++d) acc[a][b][d] = 0.f;
#pragma unroll 1
    for (int cl = 0; cl < CIN_SP; ++cl) {
#pragma unroll
        for (int ky = 0; ky < K; ++ky) {
            int yy = y + ky - PAD;
            if (yy < 0 || yy >= H) continue;
#pragma unroll
            for (int kx = 0; kx < K; ++kx) {
                int xx = x + kx - PAD;
                if (xx < 0 || xx >= W) continue;
                float4 v = *(const float4*)(sb + ((size_t)(cl * H + yy) * W + xx) * TT);
                float va[4] = {v.x, v.y, v.z, v.w};
                const float* wrow = &wlds[((cl * K + ky) * K + kx) * COUT + cb * 16];
#pragma unroll
                for (int cg = 0; cg < 4; ++cg) {
                    float4 wv = *(const float4*)(wrow + cg * 4);
                    float wa[4] = {wv.x, wv.y, wv.z, wv.w};
#pragma unroll
                    for (int c = 0; c < 4; ++c)
#pragma unroll
                        for (int tt = 0; tt < 4; ++tt)
                            acc[cg][c][tt] += wa[c] * va[tt];
                }
            }
        }
    }
    float* zb = z + (((size_t)(sp * NBATCH + n) * COUT + cb * 16) * H * W + (size_t)y * W + x) * TT + tc * 4;
#pragma unroll
    for (int cg = 0; cg < 4; ++cg)
#pragma unroll
        for (int c = 0; c < 4; ++c) {
            float4 o; o.x = acc[cg][c][0]; o.y = acc[cg][c][1]; o.z = acc[cg][c][2]; o.w = acc[cg][c][3];
            *(float4*)(zb + (size_t)(cg * 4 + c) * H * W * TT) = o;
        }
}

// FC with f-split: partial z[sp][n][o][t] = sum_{f in chunk sp} s[n][f][t]*w[o][f].
template <int OUT, int FIN, int OPER, int FSPLIT>
__global__ void k_fc_a(const float* __restrict__ s, const float* __restrict__ wgt,
                       float* __restrict__ z) {
    constexpr int OG = OUT / OPER, FCH = FIN / FSPLIT;
    int idx = blockIdx.x * 256 + threadIdx.x;
    if (idx >= NBATCH * OG * TC * FSPLIT) return;
    int tc = idx % TC;
    int og = (idx / TC) % OG;
    int n  = (idx / (TC * OG)) % NBATCH;
    int sp = idx / (TC * OG * NBATCH);
    const float* sb = s + (size_t)n * FIN * TT + (size_t)sp * FCH * TT + tc * 4;
    const float* wb = wgt + (size_t)sp * FCH;
    float acc[OPER][4];
#pragma unroll
    for (int k = 0; k < OPER; ++k) { acc[k][0] = acc[k][1] = acc[k][2] = acc[k][3] = 0.f; }
#pragma unroll 2
    for (int f = 0; f < FCH; f += 4) {
        float4 s0 = *(const float4*)(sb + (size_t)(f + 0) * TT);
        float4 s1 = *(const float4*)(sb + (size_t)(f + 1) * TT);
        float4 s2 = *(const float4*)(sb + (size_t)(f + 2) * TT);
        float4 s3 = *(const float4*)(sb + (size_t)(f + 3) * TT);
#pragma unroll
        for (int k = 0; k < OPER; ++k) {
            float4 wv = *(const float4*)(wb + (size_t)(og * OPER + k) * FIN + f);
            acc[k][0] += wv.x * s0.x + wv.y * s1.x + wv.z * s2.x + wv.w * s3.x;
            acc[k][1] += wv.x * s0.y + wv.y * s1.y + wv.z * s2.y + wv.w * s3.y;
            acc[k][2] += wv.x * s0.z + wv.y * s1.z + wv.z * s2.z + wv.w * s3.z;
            acc[k][3] += wv.x * s0.w + wv.y * s1.w + wv.z * s2.w + wv.w * s3.w;
        }
    }
#pragma unroll
    for (int k = 0; k < OPER; ++k) {
        float4 o; o.x = acc[k][0]; o.y = acc[k][1]; o.z = acc[k][2]; o.w = acc[k][3];
        *(float4*)(z + ((size_t)sp * NBATCH * OUT + (size_t)n * OUT + og * OPER + k) * TT + tc * 4) = o;
    }
}

extern "C" void kernel_launch(void* const* d_in, const int* in_sizes, int n_in,
                              void* d_out, int out_size, void* d_ws, size_t ws_size,
                              hipStream_t stream) {
    const float* s_in = (const float*)d_in[0]; // (4,2,128,128,300)
    const float* w1   = (const float*)d_in[1]; // (32,2,5,5)
    const float* w2   = (const float*)d_in[2]; // (64,32,3,3)
    const float* w3   = (const float*)d_in[3]; // (64,64,3,3)
    const float* w4a  = (const float*)d_in[4]; // (256,4096)
    const float* w4b  = (const float*)d_in[5]; // (11,256)
    float* out = (float*)d_out;                // (4,11,300)

    // Workspace (floats): Z 49,152,000 (s2 9.83M | z3 39.3M overlaid with z5/z6/z7)
    // | Sb 9,830,400 (s0/s4/s5/s6 time-multiplexed) | w2p/w3p packs. Total 236.2 MB
    // (r2 ran 236.4 MB successfully).
    float* Z  = (float*)d_ws;
    float* Sb = Z + 49152000;
    float* WP = Sb + 9830400;
    float* w2p = WP;           // 288*64 = 18432
    float* w3p = WP + 18432;   // 576*64 = 36864

    auto g = [](int n) { return (n + 255) / 256; };
    auto g64 = [](int n) { return (n + 63) / 64; };

    k_pack_w<<<g(18432), 256, 0, stream>>>(w2, w2p, 288, 64, 18432);
    k_pack_w<<<g(36864), 256, 0, stream>>>(w3, w3p, 576, 64, 36864);

    // L0: 4x4 pool + psp -> s0 (4,2,32,32,300) @ Sb
    k_pool4<<<g(614400), 256, 0, stream>>>(s_in, Z);
    k_scan_redp<1><<<g64(8192), 64, 0, stream>>>(Z, Sb, 8192, 0);

    // L1+L2 fully fused: conv 5x5 + psp + 2x2 pool + psp -> s2 (4,32,16,16,300) @ Z
    k_conv1_fused<<<512, 256, 0, stream>>>(Sb, w1, Z);

    // L3 conv 3x3 (32->64, 16x16), ci-split 2: z3 (2 x 19.66M) @ Z+9830400. 2400 blocks.
    k_conv_lds<2, 32, 64, 16, 16, 3, 1><<<2400, 256, 0, stream>>>(Z, w2p, Z + 9830400);
    // L3 psp + 2x2 pool + L4 psp -> s4 (4,64,8,8,300) @ Sb. 256 blocks.
    k_spsq<2, 64, 8, 8><<<256, 256, 0, stream>>>(Z + 9830400, Sb, 19660800);

    // L5 conv 3x3 (64->64, 8x8), ci-split 4: z5 (4 x 4.92M) @ Z. 1200 blocks.
    k_conv_lds<4, 64, 64, 8, 8, 3, 1><<<1200, 256, 0, stream>>>(Sb, w3p, Z);
    // fused 4-way reduce + scan -> s5 @ Sb+4915200
    k_scan_redp<4><<<g64(16384), 64, 0, stream>>>(Z, Sb + 4915200, 16384, 4915200);

    // L6: fc 4096->256, 16-way f-split: z6 (16 x 307200) @ Z. 600 blocks.
    k_fc_a<256, 4096, 8, 16><<<600, 256, 0, stream>>>(Sb + 4915200, w4a, Z);
    k_reduce<16><<<g(76800), 256, 0, stream>>>(Z, Z + 4915200, 76800, 307200);
    k_scan_redp<1><<<g64(1024), 64, 0, stream>>>(Z + 4915200, Sb, 1024, 0);

    // L7: fc 256->11 + psp -> out
    k_fc_a<11, 256, 1, 1><<<g(3300), 256, 0, stream>>>(Sb, w4b, Z);
    k_scan_redp<1><<<1, 64, 0, stream>>>(Z, out, 44, 0);
}